// Round 1
// baseline (579.869 us; speedup 1.0000x reference)
//
#include <hip/hip_runtime.h>
#include <hip/hip_bf16.h>
#include <math.h>

#define Bn 8
#define Nn 8192
#define KIN 1024
#define DOUT 512
#define NC 64
#define LN_EPS 1e-5f

typedef short bf16x8 __attribute__((ext_vector_type(8)));
typedef short s4v __attribute__((ext_vector_type(4)));
typedef short s8v __attribute__((ext_vector_type(8)));
typedef float f32x4 __attribute__((ext_vector_type(4)));

__device__ __forceinline__ short f2bf(float f) {
    __hip_bfloat16 h = __float2bfloat16(f);
    return __builtin_bit_cast(short, h);
}

__device__ __forceinline__ void load_lds16(const void* g, void* l) {
    __builtin_amdgcn_global_load_lds(
        (const __attribute__((address_space(1))) unsigned int*)g,
        (__attribute__((address_space(3))) unsigned int*)l, 16, 0, 0);
}

// ---------------- prep: W_node^T -> bf16 [512][1024] ----------------
__global__ void k_prep_w(const float* __restrict__ W, short* __restrict__ Wt) {
    int o = blockIdx.x * 256 + threadIdx.x;     // 524288
    int n = o >> 10, k = o & 1023;
    Wt[o] = f2bf(W[k * DOUT + n]);
}

// ---------------- prep: ccp = cc @ Wc + bc  (fp32 + bf16) ----------------
__global__ void k_prep_c(const float* __restrict__ cc, const float* __restrict__ Wc,
                         const float* __restrict__ bc, float* __restrict__ ccp_f,
                         short* __restrict__ ccp_bf) {
    int o = blockIdx.x * 256 + threadIdx.x;     // 32768
    int c = o >> 9, n = o & 511;
    float a = bc[n];
    for (int k = 0; k < DOUT; ++k) a += cc[c * DOUT + k] * Wc[k * DOUT + n];
    ccp_f[o] = a;
    ccp_bf[o] = f2bf(a);
}

// ---------------- GEMM1: proj[65536][512] bf16 = A(fp32)@W + b ----------------
// BM=64, BN=512 (full N: A read once from HBM), BK=32, 512 thr = 8 waves,
// wave tile 64x64 -> 16 MFMA : 8 ds_read_b128 per K-iter (m97-like ratio).
__global__ __launch_bounds__(512) void k_gemm1(
    const float* __restrict__ A, const short* __restrict__ Wt,
    const float* __restrict__ bias, short* __restrict__ proj) {
    __shared__ short As[64 * 32];
    __shared__ short Bs[512 * 32];
    const int tid = threadIdx.x;
    const int lane = tid & 63, wv = tid >> 6;   // wv = n-group 0..7
    const int quad = lane >> 4, l15 = lane & 15;
    const int m0 = blockIdx.x * 64;

    f32x4 acc[4][4];
#pragma unroll
    for (int i = 0; i < 4; ++i)
#pragma unroll
        for (int j = 0; j < 4; ++j) acc[i][j] = (f32x4){0.f, 0.f, 0.f, 0.f};

    const int ar = tid >> 3;            // 0..63 A row
    const int akq = (tid & 7) * 4;      // col group of 4
    const float* Ag = A + (size_t)(m0 + ar) * KIN + akq;

    for (int it = 0; it < KIN / 32; ++it) {
        __syncthreads();
        const int k0 = it * 32;
        // A: 64x32 fp32 -> bf16, one float4 per thread
        {
            float4 av = *reinterpret_cast<const float4*>(Ag + k0);
            s4v pv;
            pv.x = f2bf(av.x); pv.y = f2bf(av.y); pv.z = f2bf(av.z); pv.w = f2bf(av.w);
            *reinterpret_cast<s4v*>(&As[ar * 32 + akq]) = pv;
        }
        // B: 512x32 bf16 via global_load_lds, 4 chunks of 16B per thread
#pragma unroll
        for (int iss = 0; iss < 4; ++iss) {
            int c = iss * 512 + tid;
            int n = c >> 2, kc = c & 3;
            load_lds16(Wt + n * KIN + k0 + kc * 8, Bs + (iss * 512 + wv * 64) * 8);
        }
        __syncthreads();
        bf16x8 af[4], bfr[4];
#pragma unroll
        for (int mi = 0; mi < 4; ++mi)
            af[mi] = *reinterpret_cast<const bf16x8*>(&As[(mi * 16 + l15) * 32 + quad * 8]);
#pragma unroll
        for (int ni = 0; ni < 4; ++ni)
            bfr[ni] = *reinterpret_cast<const bf16x8*>(&Bs[(wv * 64 + ni * 16 + l15) * 32 + quad * 8]);
#pragma unroll
        for (int mi = 0; mi < 4; ++mi)
#pragma unroll
            for (int ni = 0; ni < 4; ++ni)
                acc[mi][ni] = __builtin_amdgcn_mfma_f32_16x16x32_bf16(af[mi], bfr[ni], acc[mi][ni], 0, 0, 0);
    }
    // epilogue: + bias, store bf16. C/D: row(m)=quad*4+r, col(n)=l15
#pragma unroll
    for (int ni = 0; ni < 4; ++ni) {
        int col = wv * 64 + ni * 16 + l15;
        float bv = bias[col];
#pragma unroll
        for (int mi = 0; mi < 4; ++mi)
#pragma unroll
            for (int r = 0; r < 4; ++r) {
                int row = m0 + mi * 16 + quad * 4 + r;
                proj[(size_t)row * DOUT + col] = f2bf(acc[mi][ni][r] + bv);
            }
    }
}

// ---------------- sims[b][c][n] = ccp . proj  (K=512) -> d_out aw region ----------------
__global__ __launch_bounds__(256) void k_sims(
    const short* __restrict__ ccp_bf, const short* __restrict__ proj,
    float* __restrict__ sims) {
    __shared__ short As[64 * 32];
    __shared__ short Bs[128 * 32];
    const int tid = threadIdx.x, lane = tid & 63, wv = tid >> 6;
    const int quad = lane >> 4, l15 = lane & 15;
    const int b = blockIdx.x >> 6, nt = blockIdx.x & 63;
    const int n0 = nt * 128;
    const int wm = wv >> 1, wn = wv & 1;  // wave tile 32(c) x 64(n)

    f32x4 acc[2][4];
#pragma unroll
    for (int i = 0; i < 2; ++i)
#pragma unroll
        for (int j = 0; j < 4; ++j) acc[i][j] = (f32x4){0.f, 0.f, 0.f, 0.f};

    for (int it = 0; it < DOUT / 32; ++it) {
        __syncthreads();
        const int k0 = it * 32;
        {   // A: 64x32 (ccp), 256 chunks
            int r = tid >> 2, kc = tid & 3;
            load_lds16(ccp_bf + r * DOUT + k0 + kc * 8, As + wv * 64 * 8);
        }
#pragma unroll
        for (int iss = 0; iss < 2; ++iss) {  // B: 128x32 (proj rows)
            int c = iss * 256 + tid;
            int r = c >> 2, kc = c & 3;
            load_lds16(proj + (size_t)(b * Nn + n0 + r) * DOUT + k0 + kc * 8,
                       Bs + (iss * 256 + wv * 64) * 8);
        }
        __syncthreads();
        bf16x8 af[2], bfr[4];
#pragma unroll
        for (int mi = 0; mi < 2; ++mi)
            af[mi] = *reinterpret_cast<const bf16x8*>(&As[(wm * 32 + mi * 16 + l15) * 32 + quad * 8]);
#pragma unroll
        for (int ni = 0; ni < 4; ++ni)
            bfr[ni] = *reinterpret_cast<const bf16x8*>(&Bs[(wn * 64 + ni * 16 + l15) * 32 + quad * 8]);
#pragma unroll
        for (int mi = 0; mi < 2; ++mi)
#pragma unroll
            for (int ni = 0; ni < 4; ++ni)
                acc[mi][ni] = __builtin_amdgcn_mfma_f32_16x16x32_bf16(af[mi], bfr[ni], acc[mi][ni], 0, 0, 0);
    }
#pragma unroll
    for (int mi = 0; mi < 2; ++mi)
#pragma unroll
        for (int ni = 0; ni < 4; ++ni)
#pragma unroll
            for (int r = 0; r < 4; ++r) {
                int c = wm * 32 + mi * 16 + quad * 4 + r;
                int n = n0 + wn * 64 + ni * 16 + l15;
                sims[((size_t)b * NC + c) * Nn + n] = acc[mi][ni][r];
            }
}

// ---------------- softmax over n (in-place on d_out) + bf16 copy ----------------
__global__ __launch_bounds__(256) void k_softmax(
    float* __restrict__ aw, const unsigned char* __restrict__ mask,
    short* __restrict__ aw_bf) {
    __shared__ float red[8];
    const int tid = threadIdx.x, lane = tid & 63, wv = tid >> 6;
    const int b = blockIdx.x >> 6, c = blockIdx.x & 63;
    float* p = aw + ((size_t)b * NC + c) * Nn;
    short* q = aw_bf + ((size_t)b * NC + c) * Nn;
    const unsigned char* mp = mask + b * Nn;

    float v[32];
    float mx = -INFINITY;
#pragma unroll
    for (int i = 0; i < 32; ++i) {
        int idx = tid + i * 256;
        float x = p[idx];
        if (mp[idx]) x = -INFINITY;
        v[i] = x;
        mx = fmaxf(mx, x);
    }
    for (int off = 32; off; off >>= 1) mx = fmaxf(mx, __shfl_xor(mx, off));
    if (lane == 0) red[wv] = mx;
    __syncthreads();
    mx = fmaxf(fmaxf(red[0], red[1]), fmaxf(red[2], red[3]));
    __syncthreads();

    float s = 0.f;
#pragma unroll
    for (int i = 0; i < 32; ++i) {
        v[i] = expf(v[i] - mx);
        s += v[i];
    }
    for (int off = 32; off; off >>= 1) s += __shfl_xor(s, off);
    if (lane == 0) red[wv] = s;
    __syncthreads();
    s = red[0] + red[1] + red[2] + red[3];
    float inv = 1.f / s;
#pragma unroll
    for (int i = 0; i < 32; ++i) {
        int idx = tid + i * 256;
        float w = v[i] * inv;
        p[idx] = w;
        q[idx] = f2bf(w);
    }
}

// ---------------- aggregation: partial[b][ks][c][d] = sum_n aw*proj (split-K=8) ----------------
__global__ __launch_bounds__(256) void k_agg(
    const short* __restrict__ aw_bf, const short* __restrict__ proj,
    float* __restrict__ partial) {
    __shared__ short As[64 * 32];
    __shared__ short Bs[64 * 40];   // [d][k], pad 40 keeps b128 16B-aligned
    const int tid = threadIdx.x, lane = tid & 63, wv = tid >> 6;
    const int quad = lane >> 4, l15 = lane & 15;
    const int b = blockIdx.x >> 6, dt = (blockIdx.x >> 3) & 7, ks = blockIdx.x & 7;
    const int d0 = dt * 64;
    const int wc = wv >> 1, wd = wv & 1;  // wave 32(c) x 32(d)

    f32x4 acc[2][2];
#pragma unroll
    for (int i = 0; i < 2; ++i)
#pragma unroll
        for (int j = 0; j < 2; ++j) acc[i][j] = (f32x4){0.f, 0.f, 0.f, 0.f};

    const int bk = tid >> 3;          // 0..31: n within tile
    const int bj0 = (tid & 7) * 8;    // d offset

    for (int it = 0; it < 32; ++it) {
        const int nb = ks * 1024 + it * 32;
        __syncthreads();
        {   // A: aw rows [64 c][32 n]
            int r = tid >> 2, kc = tid & 3;
            load_lds16(aw_bf + ((size_t)b * NC + r) * Nn + nb + kc * 8, As + wv * 64 * 8);
        }
        {   // B: proj [32 n][64 d] -> transpose into Bs[d][k]
            const short* g = proj + (size_t)(b * Nn + nb + bk) * DOUT + d0 + bj0;
            s8v x = *reinterpret_cast<const s8v*>(g);
#pragma unroll
            for (int j = 0; j < 8; ++j) Bs[(bj0 + j) * 40 + bk] = x[j];
        }
        __syncthreads();
        bf16x8 af[2], bfr[2];
#pragma unroll
        for (int ci = 0; ci < 2; ++ci)
            af[ci] = *reinterpret_cast<const bf16x8*>(&As[(wc * 32 + ci * 16 + l15) * 32 + quad * 8]);
#pragma unroll
        for (int di = 0; di < 2; ++di)
            bfr[di] = *reinterpret_cast<const bf16x8*>(&Bs[(wd * 32 + di * 16 + l15) * 40 + quad * 8]);
#pragma unroll
        for (int ci = 0; ci < 2; ++ci)
#pragma unroll
            for (int di = 0; di < 2; ++di)
                acc[ci][di] = __builtin_amdgcn_mfma_f32_16x16x32_bf16(af[ci], bfr[di], acc[ci][di], 0, 0, 0);
    }
#pragma unroll
    for (int ci = 0; ci < 2; ++ci)
#pragma unroll
        for (int di = 0; di < 2; ++di)
#pragma unroll
            for (int r = 0; r < 4; ++r) {
                int c = wc * 32 + ci * 16 + quad * 4 + r;
                int d = d0 + wd * 32 + di * 16 + l15;
                partial[(((size_t)b * 8 + ks) * NC + c) * DOUT + d] = acc[ci][di][r];
            }
}

// ---------------- LN: sum partials + ccp residual, normalize, store ----------------
__global__ __launch_bounds__(256) void k_ln(
    const float* __restrict__ partial, const float* __restrict__ ccp,
    const float* __restrict__ gamma, const float* __restrict__ beta,
    float* __restrict__ out) {
    __shared__ float red[16];
    const int tid = threadIdx.x, lane = tid & 63, wv = tid >> 6;
    const int b = blockIdx.x >> 6, c = blockIdx.x & 63;
    float v0 = ccp[c * DOUT + tid], v1 = ccp[c * DOUT + tid + 256];
#pragma unroll
    for (int ks = 0; ks < 8; ++ks) {
        const float* pp = partial + (((size_t)b * 8 + ks) * NC + c) * DOUT;
        v0 += pp[tid];
        v1 += pp[tid + 256];
    }
    float s = v0 + v1, sq = v0 * v0 + v1 * v1;
    for (int off = 32; off; off >>= 1) {
        s += __shfl_xor(s, off);
        sq += __shfl_xor(sq, off);
    }
    if (lane == 0) { red[wv] = s; red[8 + wv] = sq; }
    __syncthreads();
    s = red[0] + red[1] + red[2] + red[3];
    sq = red[8] + red[9] + red[10] + red[11];
    float mu = s * (1.f / 512.f);
    float var = sq * (1.f / 512.f) - mu * mu;
    float rs = rsqrtf(var + LN_EPS);
    size_t base = ((size_t)b * NC + c) * DOUT;
    out[base + tid] = (v0 - mu) * rs * gamma[tid] + beta[tid];
    out[base + tid + 256] = (v1 - mu) * rs * gamma[tid + 256] + beta[tid + 256];
}

extern "C" void kernel_launch(void* const* d_in, const int* in_sizes, int n_in,
                              void* d_out, int out_size, void* d_ws, size_t ws_size,
                              hipStream_t stream) {
    const float* node_emb = (const float*)d_in[0];
    const unsigned char* mask = (const unsigned char*)d_in[1];
    const float* cc = (const float*)d_in[2];
    const float* Wn = (const float*)d_in[3];
    const float* bn = (const float*)d_in[4];
    const float* Wc = (const float*)d_in[5];
    const float* bc = (const float*)d_in[6];
    const float* gamma = (const float*)d_in[7];
    const float* beta = (const float*)d_in[8];
    float* out = (float*)d_out;

    char* ws = (char*)d_ws;
    short* proj   = (short*)(ws);                  // 67,108,864 B  [65536][512] bf16
    short* Wt     = (short*)(ws + 67108864);       //  1,048,576 B  [512][1024] bf16
    float* ccp_f  = (float*)(ws + 68157440);       //    131,072 B  [64][512] f32
    short* ccp_bf = (short*)(ws + 68288512);       //     65,536 B  [64][512] bf16
    short* aw_bf  = (short*)(ws + 68354048);       //  8,388,608 B  [8][64][8192] bf16
    float* partial= (float*)(ws + 76742656);       //  8,388,608 B  [8][8][64][512] f32

    float* sims = out + (size_t)Bn * NC * DOUT;    // aw region of d_out, used as scratch

    k_prep_w<<<2048, 256, 0, stream>>>(Wn, Wt);
    k_prep_c<<<128, 256, 0, stream>>>(cc, Wc, bc, ccp_f, ccp_bf);
    k_gemm1<<<1024, 512, 0, stream>>>(node_emb, Wt, bn, proj);
    k_sims<<<512, 256, 0, stream>>>(ccp_bf, proj, sims);
    k_softmax<<<512, 256, 0, stream>>>(sims, mask, aw_bf);
    k_agg<<<512, 256, 0, stream>>>(aw_bf, proj, partial);
    k_ln<<<512, 256, 0, stream>>>(partial, ccp_f, gamma, beta, out);
}